// Round 10
// baseline (39.874 us; speedup 1.0000x reference)
//
#include <hip/hip_runtime.h>

// B=32, C=1, H=W=112, O=64, KH=KW=5, stride=1 -> oh=ow=108
constexpr int KH = 5, KW = 5;
constexpr int O  = 64;
constexpr int D  = KH * KW;          // 25
constexpr int H  = 112, W = 112;
constexpr int OH = H - KH + 1;       // 108
constexpr int OW = W - KW + 1;       // 108
constexpr int P  = OH * OW;          // 11664
constexpr int BLK_PX = 256;          // pixels per block (512 thr / 8 waves)
constexpr int OSTRIDE = 264;         // obuf row stride (floats)

typedef __attribute__((ext_vector_type(8))) short short8v;       // 8 bf16
typedef __attribute__((ext_vector_type(4))) float float4v;       // MFMA acc
typedef __attribute__((ext_vector_type(4))) unsigned int uint4v; // 16B unit

// ws (shorts): whi [8 mi][64 lane][8 j] = 4096 | wlo same = 4096.  mi=Mt*2+img.
// k-slot map: k=(lane>>4)*8+j.  k<25: weights.  k==25: -0.5*||w||^2 (patch:=1).
// k==26: -0.5 (patch := a^2 hi/lo)  =>  acc = dot - n2/2 - a2/2 = -d^2/2.
constexpr size_t WS_BYTES = 8192 * sizeof(short);   // 16 KiB

__global__ void prep_weights_mfma(const float* __restrict__ gw,
                                  const float* __restrict__ rw,
                                  void* wsv) {
    short* ws = (short*)wsv;
    const int t = threadIdx.x;                 // 0..255
    for (int u = t; u < 512; u += 256) {       // (mi, lane) units
        const int lane = u & 63, mi = u >> 6;
        const int img = mi & 1, Mt = mi >> 1;
        const int hi = lane >> 4, c = lane & 15;
        const float* wt = img ? rw : gw;
        const int o = Mt * 16 + c;
        short vh[8], vl[8];
        #pragma unroll
        for (int j = 0; j < 8; ++j) {
            const int k = hi * 8 + j;
            float w;
            if (k < D) {
                w = wt[o * D + k];
            } else if (k == D) {               // -0.5*||w||^2 (patch slot = 1.0)
                float s2 = 0.f;
                for (int kk = 0; kk < D; ++kk) {
                    float x = wt[o * D + kk];
                    s2 = fmaf(x, x, s2);
                }
                w = -0.5f * s2;
            } else if (k == D + 1) {           // -0.5 (patch slot = a^2)
                w = -0.5f;
            } else {
                w = 0.f;
            }
            const unsigned bits = __float_as_uint(w);
            const float hf = __uint_as_float(bits & 0xFFFF0000u);
            vh[j] = (short)(bits >> 16);
            vl[j] = (short)(__float_as_uint(w - hf) >> 16);
        }
        short* dh = ws + (mi * 64 + lane) * 8;
        short* dl = dh + 4096;
        #pragma unroll
        for (int j = 0; j < 8; ++j) { dh[j] = vh[j]; dl[j] = vl[j]; }
    }
}

// pack two floats' top 16 bits (bf16-trunc) into one dword: low=a_hi, high=b_hi
__device__ inline unsigned pack_hi2(float a, float b) {
    return __builtin_amdgcn_perm(__float_as_uint(b), __float_as_uint(a),
                                 0x07060302u);
}

__global__ __launch_bounds__(512, 4) void rbf_mfma_t(
    const float* __restrict__ gin, const float* __restrict__ rin,
    const void* __restrict__ wsv,  const float* __restrict__ stdp,
    float* __restrict__ out)
{
    const short* wfrag = (const short*)wsv;
    __shared__ short wlo_s[4096];                  // lo weight fragments, 8 KiB
    __shared__ float obuf[64 * OSTRIDE];           // [channel][256 px + pad], 66 KiB
    {
        const short* wlo_g = wfrag + 4096;
        for (int i = threadIdx.x; i < 512; i += 512)
            ;  // (kept below: full staging loop)
        for (int i = threadIdx.x; i < 512; i += 512)
            ;
    }
    // Stage lo fragments to LDS (once per block).
    for (int i = threadIdx.x; i < 512; i += 512)
        *(uint4v*)(wlo_s + i * 8) = *(const uint4v*)((const short*)wfrag + 4096 + i * 8);

    const int lane = threadIdx.x & 63;
    const int hi   = lane >> 4;
    const int c    = lane & 15;
    const bool hi3 = (hi == 3);
    const int w    = threadIdx.x >> 6;              // wave id 0..7
    const int q0   = blockIdx.x * BLK_PX;           // block's 256 consecutive pixels

    // hi weight fragments in registers: [mi]  (32 VGPRs)
    short8v wh[8];
    #pragma unroll
    for (int mi = 0; mi < 8; ++mi)
        wh[mi] = *(const short8v*)(wfrag + (mi * 64 + lane) * 8);

    // Per-lane patch offsets for k = hi*8+j (k>=25 -> dummy 0, weight=0).
    int offs[8];
    #pragma unroll
    for (int j = 0; j < 8; ++j) {
        const int k  = hi * 8 + j;
        const int ki = k / 5, kj = k - ki * 5;
        offs[j] = (k < D) ? (ki * W + kj) : 0;
    }

    const float s   = stdp[0];
    const float k2  = -1.442695040888963f / (2.f * s * s);  // -log2e/(2s^2)
    const float k2a = -2.f * k2;
    const float k2b = 4.f * k2;

    __syncthreads();

    auto ibase_of = [&](int pxbase) -> int {
        const unsigned idxp = (unsigned)(q0 + pxbase + c);
        const unsigned bp = idxp / (unsigned)P;
        const unsigned pp = idxp - bp * (unsigned)P;
        const unsigned yy = pp / (unsigned)OW;
        const unsigned xx = pp - yy * (unsigned)OW;
        return (int)((bp * H + yy) * W + xx);
    };

    auto load8 = [&](float (&v)[8], const float* base) {
        #pragma unroll
        for (int j = 0; j < 8; ++j) v[j] = base[offs[j]];
    };

    // Validated 16x16 core: patch=A (rows=pixels), weight=B (cols=channels).
    auto process = [&](const float (&vg)[8], const float (&vr)[8], int pxbase) {
        short8v pfh[2], pfl[2];
        #pragma unroll
        for (int img = 0; img < 2; ++img) {
            const float (&v)[8] = img ? vr : vg;
            float full = 0.f;
            #pragma unroll
            for (int j = 0; j < 8; ++j) full = fmaf(v[j], v[j], full);
            float part = hi3 ? v[0] * v[0] : full;  // hi==3 owns only k=24
            part += __shfl_xor(part, 16);
            part += __shfl_xor(part, 32);           // a^2 for pixel c

            float lf[8];
            #pragma unroll
            for (int j = 0; j < 8; ++j) {
                const float hf = __uint_as_float(__float_as_uint(v[j]) & 0xFFFF0000u);
                lf[j] = v[j] - hf;
            }
            uint4v uh, ul;
            uh.x = pack_hi2(v[0], v[1]);   uh.y = pack_hi2(v[2], v[3]);
            uh.z = pack_hi2(v[4], v[5]);   uh.w = pack_hi2(v[6], v[7]);
            ul.x = pack_hi2(lf[0], lf[1]); ul.y = pack_hi2(lf[2], lf[3]);
            ul.z = pack_hi2(lf[4], lf[5]); ul.w = pack_hi2(lf[6], lf[7]);

            // Homogeneous injections (hi==3): j=1 (k=25) := 1.0/0.0 ;
            // j=2 (k=26) := a2_hi / a2_residual.
            const unsigned a2u = __float_as_uint(part);
            const float    a2t = __uint_as_float(a2u & 0xFFFF0000u);
            const unsigned aru = __float_as_uint(part - a2t);
            uh.x = hi3 ? ((uh.x & 0x0000FFFFu) | 0x3F800000u) : uh.x;
            ul.x = hi3 ? (ul.x & 0x0000FFFFu) : ul.x;
            uh.y = hi3 ? ((uh.y & 0xFFFF0000u) | (a2u >> 16)) : uh.y;
            ul.y = hi3 ? ((ul.y & 0xFFFF0000u) | (aru >> 16)) : ul.y;

            pfh[img] = __builtin_bit_cast(short8v, uh);
            pfl[img] = __builtin_bit_cast(short8v, ul);
        }

        const float4v z4 = {0.f, 0.f, 0.f, 0.f};
        #pragma unroll
        for (int Mt = 0; Mt < 4; ++Mt) {
            const short8v wlg = *(const short8v*)(wlo_s + ((Mt * 2 + 0) * 64 + lane) * 8);
            const short8v wlr = *(const short8v*)(wlo_s + ((Mt * 2 + 1) * 64 + lane) * 8);
            float4v ag4 = __builtin_amdgcn_mfma_f32_16x16x32_bf16(pfh[0], wh[Mt * 2 + 0], z4, 0, 0, 0);
            ag4 = __builtin_amdgcn_mfma_f32_16x16x32_bf16(pfh[0], wlg, ag4, 0, 0, 0);
            ag4 = __builtin_amdgcn_mfma_f32_16x16x32_bf16(pfl[0], wh[Mt * 2 + 0], ag4, 0, 0, 0);
            float4v ar4 = __builtin_amdgcn_mfma_f32_16x16x32_bf16(pfh[1], wh[Mt * 2 + 1], z4, 0, 0, 0);
            ar4 = __builtin_amdgcn_mfma_f32_16x16x32_bf16(pfh[1], wlr, ar4, 0, 0, 0);
            ar4 = __builtin_amdgcn_mfma_f32_16x16x32_bf16(pfl[1], wh[Mt * 2 + 1], ar4, 0, 0, 0);

            // D map (validated): row = pixel = hi*4+reg, col = channel = c.
            #pragma unroll
            for (int reg = 0; reg < 4; ++reg) {
                const float g = fminf(ag4[reg], 0.f);   // acc = -d^2/2
                const float r = fminf(ar4[reg], 0.f);
                const float e = __builtin_amdgcn_exp2f(
                    fmaf(k2a, g + r, k2b * __builtin_amdgcn_sqrtf(g * r)));
                obuf[(Mt * 16 + c) * OSTRIDE + pxbase + hi * 4 + reg] = e;
            }
        }
    };

    // Two 16-pixel tiles per wave; prefetch both tiles' loads first (ILP).
    const int px0 = w * 16;            // tile 0 base (pixels 0..127 half)
    const int px1 = 128 + w * 16;      // tile 1 base (pixels 128..255 half)
    const int ib0 = ibase_of(px0);
    const int ib1 = ibase_of(px1);
    float v0g[8], v0r[8], v1g[8], v1r[8];
    load8(v0g, gin + ib0); load8(v0r, rin + ib0);
    load8(v1g, gin + ib1); load8(v1r, rin + ib1);
    process(v0g, v0r, px0);
    process(v1g, v1r, px1);

    __syncthreads();

    // Store: wave owns 8 channel rows; one dwordx4 per row = 64 lanes x 16B
    // = 1KB contiguous. Blocks straddling a batch boundary take scalar path.
    const int q0m = q0 % P;
    const bool straddle = (q0m + BLK_PX > P);
    if (!straddle) {
        const int bs = q0 / P;
        float* obase = out + (size_t)bs * O * P + q0m;
        #pragma unroll
        for (int i = 0; i < 8; ++i) {
            const int o = w * 8 + i;
            const float4v vv = *(const float4v*)(&obuf[o * OSTRIDE + 4 * lane]);
            *(float4v*)(obase + (size_t)o * P + 4 * lane) = vv;
        }
    } else {
        #pragma unroll
        for (int i = 0; i < 8; ++i) {
            const int o = w * 8 + i;
            #pragma unroll
            for (int jj = 0; jj < 4; ++jj) {
                const int px = 4 * lane + jj;
                const unsigned idxs = (unsigned)(q0 + px);
                const unsigned bs = idxs / (unsigned)P;
                const unsigned ps = idxs - bs * (unsigned)P;
                out[(size_t)bs * O * P + (size_t)o * P + ps] = obuf[o * OSTRIDE + px];
            }
        }
    }
}

// Fallback (round-1 kernel, known-correct) if ws is too small.
__global__ __launch_bounds__(256) void rbf_conv_fallback(
    const float* __restrict__ gin, const float* __restrict__ rin,
    const float* __restrict__ gw,  const float* __restrict__ rw,
    const float* __restrict__ stdp, float* __restrict__ out, int B)
{
    __shared__ float s_w2g[O], s_w2r[O];
    const int t = threadIdx.x;
    if (t < O) {
        float sg = 0.f, sr = 0.f;
        #pragma unroll
        for (int k = 0; k < D; ++k) {
            float a = gw[t * D + k]; sg = fmaf(a, a, sg);
            float b = rw[t * D + k]; sr = fmaf(b, b, sr);
        }
        s_w2g[t] = sg;
        s_w2r[t] = sr;
    }
    __syncthreads();

    const int idx = blockIdx.x * blockDim.x + t;
    if (idx >= B * P) return;
    const int b = idx / P;
    const int p = idx - b * P;
    const int y = p / OW;
    const int x = p - y * OW;

    const float* gb = gin + (b * H + y) * W + x;
    const float* rb = rin + (b * H + y) * W + x;
    float ga[D], ra[D];
    float a2g = 0.f, a2r = 0.f;
    #pragma unroll
    for (int i = 0; i < KH; ++i)
        #pragma unroll
        for (int j = 0; j < KW; ++j) {
            float g = gb[i * W + j]; ga[i * KW + j] = g; a2g = fmaf(g, g, a2g);
            float r = rb[i * W + j]; ra[i * KW + j] = r; a2r = fmaf(r, r, a2r);
        }

    const float s    = stdp[0];
    const float ninv = -1.0f / (2.0f * s * s);
    float* ob = out + (size_t)b * O * P + p;

    for (int o = 0; o < O; ++o) {
        float dg = 0.f, dr = 0.f;
        #pragma unroll
        for (int k = 0; k < D; ++k) {
            dg = fmaf(ga[k], gw[o * D + k], dg);
            dr = fmaf(ra[k], rw[o * D + k], dr);
        }
        float d2g = fmaxf(a2g + s_w2g[o] - 2.0f * dg, 0.f);
        float d2r = fmaxf(a2r + s_w2r[o] - 2.0f * dr, 0.f);
        float dist = __fsqrt_rn(d2g) + __fsqrt_rn(d2r);
        ob[(size_t)o * P] = __expf(ninv * dist * dist);
    }
}

extern "C" void kernel_launch(void* const* d_in, const int* in_sizes, int n_in,
                              void* d_out, int out_size, void* d_ws, size_t ws_size,
                              hipStream_t stream) {
    const float* gin  = (const float*)d_in[0];
    const float* rin  = (const float*)d_in[1];
    const float* gw   = (const float*)d_in[2];
    const float* rw   = (const float*)d_in[3];
    const float* stdp = (const float*)d_in[4];
    float* out = (float*)d_out;

    const int B  = in_sizes[0] / (H * W);   // 32
    const int BP = B * P;                   // 373248

    if (ws_size >= WS_BYTES && d_ws != nullptr && BP % BLK_PX == 0) {
        prep_weights_mfma<<<1, 256, 0, stream>>>(gw, rw, d_ws);
        const int blocks = BP / BLK_PX;             // 1458
        rbf_mfma_t<<<blocks, 512, 0, stream>>>(gin, rin, d_ws, stdp, out);
    } else {
        const int block = 256;
        const int grid  = (BP + block - 1) / block;
        rbf_conv_fallback<<<grid, block, 0, stream>>>(gin, rin, gw, rw, stdp, out, B);
    }
}

// Round 11
// 34.497 us; speedup vs baseline: 1.1559x; 1.1559x over previous
//
#include <hip/hip_runtime.h>

// B=32, C=1, H=W=112, O=64, KH=KW=5, stride=1 -> oh=ow=108
constexpr int KH = 5, KW = 5;
constexpr int O  = 64;
constexpr int D  = KH * KW;          // 25
constexpr int H  = 112, W = 112;
constexpr int OH = H - KH + 1;       // 108
constexpr int OW = W - KW + 1;       // 108
constexpr int P  = OH * OW;          // 11664

typedef __attribute__((ext_vector_type(8))) short short8v;       // 8 bf16
typedef __attribute__((ext_vector_type(4))) float float4v;       // MFMA acc
typedef __attribute__((ext_vector_type(4))) unsigned int uint4v; // 16B unit

// ws (shorts): whi [8 mi][64 lane][8 j] = 4096 | wlo same = 4096.  mi=Mt*2+img.
// k-slot map: k=(lane>>4)*8+j.  k<25: weights.  k==25: -0.5*||w||^2 (patch:=1).
// k==26: -0.5 (patch := a^2 hi/lo)  =>  acc = dot - n2/2 - a2/2 = -d^2/2.
constexpr size_t WS_BYTES = 8192 * sizeof(short);   // 16 KiB

__global__ void prep_weights_mfma(const float* __restrict__ gw,
                                  const float* __restrict__ rw,
                                  void* wsv) {
    short* ws = (short*)wsv;
    const int t = threadIdx.x;                 // 0..255
    for (int u = t; u < 512; u += 256) {       // (mi, lane) units
        const int lane = u & 63, mi = u >> 6;
        const int img = mi & 1, Mt = mi >> 1;
        const int hi = lane >> 4, c = lane & 15;
        const float* wt = img ? rw : gw;
        const int o = Mt * 16 + c;
        short vh[8], vl[8];
        #pragma unroll
        for (int j = 0; j < 8; ++j) {
            const int k = hi * 8 + j;
            float w;
            if (k < D) {
                w = wt[o * D + k];
            } else if (k == D) {               // -0.5*||w||^2 (patch slot = 1.0)
                float s2 = 0.f;
                for (int kk = 0; kk < D; ++kk) {
                    float x = wt[o * D + kk];
                    s2 = fmaf(x, x, s2);
                }
                w = -0.5f * s2;
            } else if (k == D + 1) {           // -0.5 (patch slot = a^2)
                w = -0.5f;
            } else {
                w = 0.f;
            }
            const unsigned bits = __float_as_uint(w);
            const float hf = __uint_as_float(bits & 0xFFFF0000u);
            vh[j] = (short)(bits >> 16);
            vl[j] = (short)(__float_as_uint(w - hf) >> 16);
        }
        short* dh = ws + (mi * 64 + lane) * 8;
        short* dl = dh + 4096;
        #pragma unroll
        for (int j = 0; j < 8; ++j) { dh[j] = vh[j]; dl[j] = vl[j]; }
    }
}

// pack two floats' top 16 bits (bf16-trunc) into one dword: low=a_hi, high=b_hi
__device__ inline unsigned pack_hi2(float a, float b) {
    return __builtin_amdgcn_perm(__float_as_uint(b), __float_as_uint(a),
                                 0x07060302u);
}

__global__ __launch_bounds__(256, 4) void rbf_mfma_t(
    const float* __restrict__ gin, const float* __restrict__ rin,
    const void* __restrict__ wsv,  const float* __restrict__ stdp,
    float* __restrict__ out)
{
    const short* wfrag = (const short*)wsv;
    __shared__ short wlo_s[4096];              // lo weight fragments, 8 KiB
    __shared__ float obuf[64 * 65];            // [channel][pixel64] +pad, 16.25 KiB
    {
        const short* wlo_g = wfrag + 4096;
        for (int i = threadIdx.x; i < 512; i += 256)
            *(uint4v*)(wlo_s + i * 8) = *(const uint4v*)(wlo_g + i * 8);
    }

    // XCD-aware bijective swizzle (gridDim.x == 5832, divisible by 8):
    // consecutive pixel-blocks land on the SAME XCD so the 64B-misaligned
    // boundary lines of odd channel rows merge in one L2 (single fetch +
    // single write-back instead of duplicate per-XCD write-allocate).
    int pb = blockIdx.x;
    {
        const int nblk = gridDim.x;
        if ((nblk & 7) == 0) {
            const int cpx = nblk >> 3;
            pb = (blockIdx.x & 7) * cpx + (blockIdx.x >> 3);
        }
    }

    const int lane = threadIdx.x & 63;
    const int hi   = lane >> 4;
    const int c    = lane & 15;
    const bool hi3 = (hi == 3);
    const int w    = threadIdx.x >> 6;          // wave id in block (0..3)
    const int q0   = pb * 64;                   // block's 64 consecutive pixels
    const int pw   = q0 + w * 16;               // this wave's 16-pixel tile

    // hi weight fragments in registers: [mi]  (32 VGPRs)
    short8v wh[8];
    #pragma unroll
    for (int mi = 0; mi < 8; ++mi)
        wh[mi] = *(const short8v*)(wfrag + (mi * 64 + lane) * 8);

    // Per-lane patch offsets for k = hi*8+j (k>=25 -> dummy 0, weight=0).
    int offs[8];
    #pragma unroll
    for (int j = 0; j < 8; ++j) {
        const int k  = hi * 8 + j;
        const int ki = k / 5, kj = k - ki * 5;
        offs[j] = (k < D) ? (ki * W + kj) : 0;
    }

    const float s   = stdp[0];
    const float k2  = -1.442695040888963f / (2.f * s * s);  // -log2e/(2s^2)
    const float k2a = -2.f * k2;
    const float k2b = 4.f * k2;

    __syncthreads();

    // ---- compute (validated 16x16 core: patch=A rows=pixels, weight=B cols=o)
    const unsigned idxp = (unsigned)(pw + c);   // this lane's pixel
    const unsigned bp = idxp / (unsigned)P;
    const unsigned pp = idxp - bp * (unsigned)P;
    const unsigned yy = pp / (unsigned)OW;
    const unsigned xx = pp - yy * (unsigned)OW;
    const int ibase = (int)((bp * H + yy) * W + xx);

    short8v pfh[2], pfl[2];
    #pragma unroll
    for (int img = 0; img < 2; ++img) {
        const float* base = (img ? rin : gin) + ibase;
        float v[8];
        #pragma unroll
        for (int j = 0; j < 8; ++j) v[j] = base[offs[j]];

        float full = 0.f;
        #pragma unroll
        for (int j = 0; j < 8; ++j) full = fmaf(v[j], v[j], full);
        float part = hi3 ? v[0] * v[0] : full;  // hi==3 owns only k=24
        part += __shfl_xor(part, 16);
        part += __shfl_xor(part, 32);           // a^2 for pixel c

        float lf[8];
        #pragma unroll
        for (int j = 0; j < 8; ++j) {
            const float hf = __uint_as_float(__float_as_uint(v[j]) & 0xFFFF0000u);
            lf[j] = v[j] - hf;
        }
        uint4v uh, ul;
        uh.x = pack_hi2(v[0], v[1]);   uh.y = pack_hi2(v[2], v[3]);
        uh.z = pack_hi2(v[4], v[5]);   uh.w = pack_hi2(v[6], v[7]);
        ul.x = pack_hi2(lf[0], lf[1]); ul.y = pack_hi2(lf[2], lf[3]);
        ul.z = pack_hi2(lf[4], lf[5]); ul.w = pack_hi2(lf[6], lf[7]);

        // Homogeneous injections (hi==3): j=1 (k=25) := 1.0/0.0 ;
        // j=2 (k=26) := a2_hi / a2_residual.
        const unsigned a2u = __float_as_uint(part);
        const float    a2t = __uint_as_float(a2u & 0xFFFF0000u);
        const unsigned aru = __float_as_uint(part - a2t);
        uh.x = hi3 ? ((uh.x & 0x0000FFFFu) | 0x3F800000u) : uh.x;
        ul.x = hi3 ? (ul.x & 0x0000FFFFu) : ul.x;
        uh.y = hi3 ? ((uh.y & 0xFFFF0000u) | (a2u >> 16)) : uh.y;
        ul.y = hi3 ? ((ul.y & 0xFFFF0000u) | (aru >> 16)) : ul.y;

        pfh[img] = __builtin_bit_cast(short8v, uh);
        pfl[img] = __builtin_bit_cast(short8v, ul);
    }

    const float4v z4 = {0.f, 0.f, 0.f, 0.f};
    #pragma unroll
    for (int Mt = 0; Mt < 4; ++Mt) {
        const short8v wlg = *(const short8v*)(wlo_s + ((Mt * 2 + 0) * 64 + lane) * 8);
        const short8v wlr = *(const short8v*)(wlo_s + ((Mt * 2 + 1) * 64 + lane) * 8);
        float4v ag4 = __builtin_amdgcn_mfma_f32_16x16x32_bf16(pfh[0], wh[Mt * 2 + 0], z4, 0, 0, 0);
        ag4 = __builtin_amdgcn_mfma_f32_16x16x32_bf16(pfh[0], wlg, ag4, 0, 0, 0);
        ag4 = __builtin_amdgcn_mfma_f32_16x16x32_bf16(pfl[0], wh[Mt * 2 + 0], ag4, 0, 0, 0);
        float4v ar4 = __builtin_amdgcn_mfma_f32_16x16x32_bf16(pfh[1], wh[Mt * 2 + 1], z4, 0, 0, 0);
        ar4 = __builtin_amdgcn_mfma_f32_16x16x32_bf16(pfh[1], wlr, ar4, 0, 0, 0);
        ar4 = __builtin_amdgcn_mfma_f32_16x16x32_bf16(pfl[1], wh[Mt * 2 + 1], ar4, 0, 0, 0);

        // D map (validated): row = pixel = (lane>>4)*4+reg, col = channel = c.
        #pragma unroll
        for (int reg = 0; reg < 4; ++reg) {
            const float g = fminf(ag4[reg], 0.f);   // acc = -d^2/2
            const float r = fminf(ar4[reg], 0.f);
            const float e = __builtin_amdgcn_exp2f(
                fmaf(k2a, g + r, k2b * __builtin_amdgcn_sqrtf(g * r)));
            obuf[(Mt * 16 + c) * 65 + w * 16 + hi * 4 + reg] = e;
        }
    }

    __syncthreads();

    // ---- store: each instruction writes one channel row x 64 consecutive
    // pixels = 256B contiguous.
    const unsigned idxs = (unsigned)(q0 + lane);
    const unsigned bs = idxs / (unsigned)P;
    const unsigned ps = idxs - bs * (unsigned)P;
    float* obase = out + (size_t)bs * O * P + ps;
    #pragma unroll
    for (int i = 0; i < 16; ++i) {
        const int o = w * 16 + i;
        obase[(size_t)o * P] = obuf[o * 65 + lane];
    }
}

// Fallback (round-1 kernel, known-correct) if ws is too small.
__global__ __launch_bounds__(256) void rbf_conv_fallback(
    const float* __restrict__ gin, const float* __restrict__ rin,
    const float* __restrict__ gw,  const float* __restrict__ rw,
    const float* __restrict__ stdp, float* __restrict__ out, int B)
{
    __shared__ float s_w2g[O], s_w2r[O];
    const int t = threadIdx.x;
    if (t < O) {
        float sg = 0.f, sr = 0.f;
        #pragma unroll
        for (int k = 0; k < D; ++k) {
            float a = gw[t * D + k]; sg = fmaf(a, a, sg);
            float b = rw[t * D + k]; sr = fmaf(b, b, sr);
        }
        s_w2g[t] = sg;
        s_w2r[t] = sr;
    }
    __syncthreads();

    const int idx = blockIdx.x * blockDim.x + t;
    if (idx >= B * P) return;
    const int b = idx / P;
    const int p = idx - b * P;
    const int y = p / OW;
    const int x = p - y * OW;

    const float* gb = gin + (b * H + y) * W + x;
    const float* rb = rin + (b * H + y) * W + x;
    float ga[D], ra[D];
    float a2g = 0.f, a2r = 0.f;
    #pragma unroll
    for (int i = 0; i < KH; ++i)
        #pragma unroll
        for (int j = 0; j < KW; ++j) {
            float g = gb[i * W + j]; ga[i * KW + j] = g; a2g = fmaf(g, g, a2g);
            float r = rb[i * W + j]; ra[i * KW + j] = r; a2r = fmaf(r, r, a2r);
        }

    const float s    = stdp[0];
    const float ninv = -1.0f / (2.0f * s * s);
    float* ob = out + (size_t)b * O * P + p;

    for (int o = 0; o < O; ++o) {
        float dg = 0.f, dr = 0.f;
        #pragma unroll
        for (int k = 0; k < D; ++k) {
            dg = fmaf(ga[k], gw[o * D + k], dg);
            dr = fmaf(ra[k], rw[o * D + k], dr);
        }
        float d2g = fmaxf(a2g + s_w2g[o] - 2.0f * dg, 0.f);
        float d2r = fmaxf(a2r + s_w2r[o] - 2.0f * dr, 0.f);
        float dist = __fsqrt_rn(d2g) + __fsqrt_rn(d2r);
        ob[(size_t)o * P] = __expf(ninv * dist * dist);
    }
}

extern "C" void kernel_launch(void* const* d_in, const int* in_sizes, int n_in,
                              void* d_out, int out_size, void* d_ws, size_t ws_size,
                              hipStream_t stream) {
    const float* gin  = (const float*)d_in[0];
    const float* rin  = (const float*)d_in[1];
    const float* gw   = (const float*)d_in[2];
    const float* rw   = (const float*)d_in[3];
    const float* stdp = (const float*)d_in[4];
    float* out = (float*)d_out;

    const int B  = in_sizes[0] / (H * W);   // 32
    const int BP = B * P;                   // 373248

    if (ws_size >= WS_BYTES && d_ws != nullptr && BP % 64 == 0) {
        prep_weights_mfma<<<1, 256, 0, stream>>>(gw, rw, d_ws);
        const int blocks = BP / 64;                 // 5832
        rbf_mfma_t<<<blocks, 256, 0, stream>>>(gin, rin, d_ws, stdp, out);
    } else {
        const int block = 256;
        const int grid  = (BP + block - 1) / block;
        rbf_conv_fallback<<<grid, block, 0, stream>>>(gin, rin, gw, rw, stdp, out, B);
    }
}

// Round 12
// 33.791 us; speedup vs baseline: 1.1800x; 1.0209x over previous
//
#include <hip/hip_runtime.h>

// B=32, C=1, H=W=112, O=64, KH=KW=5, stride=1 -> oh=ow=108
constexpr int KH = 5, KW = 5;
constexpr int O  = 64;
constexpr int D  = KH * KW;          // 25
constexpr int H  = 112, W = 112;
constexpr int OH = H - KH + 1;       // 108
constexpr int OW = W - KW + 1;       // 108
constexpr int P  = OH * OW;          // 11664

typedef __attribute__((ext_vector_type(8))) short short8v;       // 8 bf16
typedef __attribute__((ext_vector_type(4))) float float4v;       // MFMA acc
typedef __attribute__((ext_vector_type(4))) unsigned int uint4v; // 16B unit

// ws (shorts): whi [8 mi][64 lane][8 j] = 4096 | wlo same = 4096.  mi=Mt*2+img.
// k-slot map: k=(lane>>4)*8+j.  k<25: weights.  k==25: -0.5*||w||^2 (patch:=1).
// k==26: -0.5 (patch := a^2 hi/lo)  =>  acc = dot - n2/2 - a2/2 = -d^2/2.
constexpr size_t WS_BYTES = 8192 * sizeof(short);   // 16 KiB

__global__ void prep_weights_mfma(const float* __restrict__ gw,
                                  const float* __restrict__ rw,
                                  void* wsv) {
    short* ws = (short*)wsv;
    const int t = threadIdx.x;                 // 0..255
    for (int u = t; u < 512; u += 256) {       // (mi, lane) units
        const int lane = u & 63, mi = u >> 6;
        const int img = mi & 1, Mt = mi >> 1;
        const int hi = lane >> 4, c = lane & 15;
        const float* wt = img ? rw : gw;
        const int o = Mt * 16 + c;
        short vh[8], vl[8];
        #pragma unroll
        for (int j = 0; j < 8; ++j) {
            const int k = hi * 8 + j;
            float w;
            if (k < D) {
                w = wt[o * D + k];
            } else if (k == D) {               // -0.5*||w||^2 (patch slot = 1.0)
                float s2 = 0.f;
                for (int kk = 0; kk < D; ++kk) {
                    float x = wt[o * D + kk];
                    s2 = fmaf(x, x, s2);
                }
                w = -0.5f * s2;
            } else if (k == D + 1) {           // -0.5 (patch slot = a^2)
                w = -0.5f;
            } else {
                w = 0.f;
            }
            const unsigned bits = __float_as_uint(w);
            const float hf = __uint_as_float(bits & 0xFFFF0000u);
            vh[j] = (short)(bits >> 16);
            vl[j] = (short)(__float_as_uint(w - hf) >> 16);
        }
        short* dh = ws + (mi * 64 + lane) * 8;
        short* dl = dh + 4096;
        #pragma unroll
        for (int j = 0; j < 8; ++j) { dh[j] = vh[j]; dl[j] = vl[j]; }
    }
}

// pack two floats' top 16 bits (bf16-trunc) into one dword: low=a_hi, high=b_hi
__device__ inline unsigned pack_hi2(float a, float b) {
    return __builtin_amdgcn_perm(__float_as_uint(b), __float_as_uint(a),
                                 0x07060302u);
}

__global__ __launch_bounds__(256, 4) void rbf_mfma_t(
    const float* __restrict__ gin, const float* __restrict__ rin,
    const void* __restrict__ wsv,  const float* __restrict__ stdp,
    float* __restrict__ out)
{
    const short* wfrag = (const short*)wsv;
    __shared__ short wlo_s[4096];              // lo weight fragments, 8 KiB
    __shared__ float obuf[64 * 65];            // [channel][pixel64] +pad, 16.25 KiB
    {
        const short* wlo_g = wfrag + 4096;
        for (int i = threadIdx.x; i < 512; i += 256)
            *(uint4v*)(wlo_s + i * 8) = *(const uint4v*)(wlo_g + i * 8);
    }

    // XCD-aware bijective swizzle (proven neutral, kept: gridDim.x % 8 == 0).
    int pb = blockIdx.x;
    {
        const int nblk = gridDim.x;
        if ((nblk & 7) == 0) {
            const int cpx = nblk >> 3;
            pb = (blockIdx.x & 7) * cpx + (blockIdx.x >> 3);
        }
    }

    const int lane = threadIdx.x & 63;
    const int hi   = lane >> 4;
    const int c    = lane & 15;
    const bool hi3 = (hi == 3);
    const int w    = threadIdx.x >> 6;          // wave id in block (0..3)
    const int q0   = pb * 64;                   // block's 64 consecutive pixels
    const int pw   = q0 + w * 16;               // this wave's 16-pixel tile

    // hi weight fragments in registers: [mi]  (32 VGPRs)
    short8v wh[8];
    #pragma unroll
    for (int mi = 0; mi < 8; ++mi)
        wh[mi] = *(const short8v*)(wfrag + (mi * 64 + lane) * 8);

    // Per-lane patch offsets for k = hi*8+j (k>=25 -> dummy 0, weight=0).
    int offs[8];
    #pragma unroll
    for (int j = 0; j < 8; ++j) {
        const int k  = hi * 8 + j;
        const int ki = k / 5, kj = k - ki * 5;
        offs[j] = (k < D) ? (ki * W + kj) : 0;
    }

    const float s   = stdp[0];
    const float k2  = -1.442695040888963f / (2.f * s * s);  // -log2e/(2s^2)
    const float k2a = -2.f * k2;
    const float k2b = 4.f * k2;

    __syncthreads();

    // ---- compute (validated 16x16 core: patch=A rows=pixels, weight=B cols=o)
    const unsigned idxp = (unsigned)(pw + c);   // this lane's pixel
    const unsigned bp = idxp / (unsigned)P;
    const unsigned pp = idxp - bp * (unsigned)P;
    const unsigned yy = pp / (unsigned)OW;
    const unsigned xx = pp - yy * (unsigned)OW;
    const int ibase = (int)((bp * H + yy) * W + xx);

    short8v pfh[2], pfl[2];
    #pragma unroll
    for (int img = 0; img < 2; ++img) {
        const float* base = (img ? rin : gin) + ibase;
        float v[8];
        #pragma unroll
        for (int j = 0; j < 8; ++j) v[j] = base[offs[j]];

        float full = 0.f;
        #pragma unroll
        for (int j = 0; j < 8; ++j) full = fmaf(v[j], v[j], full);
        float part = hi3 ? v[0] * v[0] : full;  // hi==3 owns only k=24
        part += __shfl_xor(part, 16);
        part += __shfl_xor(part, 32);           // a^2 for pixel c

        float lf[8];
        #pragma unroll
        for (int j = 0; j < 8; ++j) {
            const float hf = __uint_as_float(__float_as_uint(v[j]) & 0xFFFF0000u);
            lf[j] = v[j] - hf;
        }
        uint4v uh, ul;
        uh.x = pack_hi2(v[0], v[1]);   uh.y = pack_hi2(v[2], v[3]);
        uh.z = pack_hi2(v[4], v[5]);   uh.w = pack_hi2(v[6], v[7]);
        ul.x = pack_hi2(lf[0], lf[1]); ul.y = pack_hi2(lf[2], lf[3]);
        ul.z = pack_hi2(lf[4], lf[5]); ul.w = pack_hi2(lf[6], lf[7]);

        // Homogeneous injections (hi==3): j=1 (k=25) := 1.0/0.0 ;
        // j=2 (k=26) := a2_hi / a2_residual.
        const unsigned a2u = __float_as_uint(part);
        const float    a2t = __uint_as_float(a2u & 0xFFFF0000u);
        const unsigned aru = __float_as_uint(part - a2t);
        uh.x = hi3 ? ((uh.x & 0x0000FFFFu) | 0x3F800000u) : uh.x;
        ul.x = hi3 ? (ul.x & 0x0000FFFFu) : ul.x;
        uh.y = hi3 ? ((uh.y & 0xFFFF0000u) | (a2u >> 16)) : uh.y;
        ul.y = hi3 ? ((ul.y & 0xFFFF0000u) | (aru >> 16)) : ul.y;

        pfh[img] = __builtin_bit_cast(short8v, uh);
        pfl[img] = __builtin_bit_cast(short8v, ul);
    }

    const float4v z4 = {0.f, 0.f, 0.f, 0.f};
    #pragma unroll
    for (int Mt = 0; Mt < 4; ++Mt) {
        const short8v wlg = *(const short8v*)(wlo_s + ((Mt * 2 + 0) * 64 + lane) * 8);
        const short8v wlr = *(const short8v*)(wlo_s + ((Mt * 2 + 1) * 64 + lane) * 8);
        float4v ag4 = __builtin_amdgcn_mfma_f32_16x16x32_bf16(pfh[0], wh[Mt * 2 + 0], z4, 0, 0, 0);
        ag4 = __builtin_amdgcn_mfma_f32_16x16x32_bf16(pfh[0], wlg, ag4, 0, 0, 0);
        ag4 = __builtin_amdgcn_mfma_f32_16x16x32_bf16(pfl[0], wh[Mt * 2 + 0], ag4, 0, 0, 0);
        float4v ar4 = __builtin_amdgcn_mfma_f32_16x16x32_bf16(pfh[1], wh[Mt * 2 + 1], z4, 0, 0, 0);
        ar4 = __builtin_amdgcn_mfma_f32_16x16x32_bf16(pfh[1], wlr, ar4, 0, 0, 0);
        ar4 = __builtin_amdgcn_mfma_f32_16x16x32_bf16(pfl[1], wh[Mt * 2 + 1], ar4, 0, 0, 0);

        // D map (validated): row = pixel = (lane>>4)*4+reg, col = channel = c.
        #pragma unroll
        for (int reg = 0; reg < 4; ++reg) {
            const float g = fminf(ag4[reg], 0.f);   // acc = -d^2/2
            const float r = fminf(ar4[reg], 0.f);
            const float e = __builtin_amdgcn_exp2f(
                fmaf(k2a, g + r, k2b * __builtin_amdgcn_sqrtf(g * r)));
            obuf[(Mt * 16 + c) * 65 + w * 16 + hi * 4 + reg] = e;
        }
    }

    __syncthreads();

    // ---- store: one channel row x 64 consecutive pixels (256B) per
    // instruction, NON-TEMPORAL: stream past L2 so partial-128B-line stores
    // (odd channel rows start at byte 64 mod 128, since P*4 = 46656) do not
    // trigger write-allocate fetch + double write-back.
    const unsigned idxs = (unsigned)(q0 + lane);
    const unsigned bs = idxs / (unsigned)P;
    const unsigned ps = idxs - bs * (unsigned)P;
    float* obase = out + (size_t)bs * O * P + ps;
    #pragma unroll
    for (int i = 0; i < 16; ++i) {
        const int o = w * 16 + i;
        __builtin_nontemporal_store(obuf[o * 65 + lane],
                                    obase + (size_t)o * P);
    }
}

// Fallback (round-1 kernel, known-correct) if ws is too small.
__global__ __launch_bounds__(256) void rbf_conv_fallback(
    const float* __restrict__ gin, const float* __restrict__ rin,
    const float* __restrict__ gw,  const float* __restrict__ rw,
    const float* __restrict__ stdp, float* __restrict__ out, int B)
{
    __shared__ float s_w2g[O], s_w2r[O];
    const int t = threadIdx.x;
    if (t < O) {
        float sg = 0.f, sr = 0.f;
        #pragma unroll
        for (int k = 0; k < D; ++k) {
            float a = gw[t * D + k]; sg = fmaf(a, a, sg);
            float b = rw[t * D + k]; sr = fmaf(b, b, sr);
        }
        s_w2g[t] = sg;
        s_w2r[t] = sr;
    }
    __syncthreads();

    const int idx = blockIdx.x * blockDim.x + t;
    if (idx >= B * P) return;
    const int b = idx / P;
    const int p = idx - b * P;
    const int y = p / OW;
    const int x = p - y * OW;

    const float* gb = gin + (b * H + y) * W + x;
    const float* rb = rin + (b * H + y) * W + x;
    float ga[D], ra[D];
    float a2g = 0.f, a2r = 0.f;
    #pragma unroll
    for (int i = 0; i < KH; ++i)
        #pragma unroll
        for (int j = 0; j < KW; ++j) {
            float g = gb[i * W + j]; ga[i * KW + j] = g; a2g = fmaf(g, g, a2g);
            float r = rb[i * W + j]; ra[i * KW + j] = r; a2r = fmaf(r, r, a2r);
        }

    const float s    = stdp[0];
    const float ninv = -1.0f / (2.0f * s * s);
    float* ob = out + (size_t)b * O * P + p;

    for (int o = 0; o < O; ++o) {
        float dg = 0.f, dr = 0.f;
        #pragma unroll
        for (int k = 0; k < D; ++k) {
            dg = fmaf(ga[k], gw[o * D + k], dg);
            dr = fmaf(ra[k], rw[o * D + k], dr);
        }
        float d2g = fmaxf(a2g + s_w2g[o] - 2.0f * dg, 0.f);
        float d2r = fmaxf(a2r + s_w2r[o] - 2.0f * dr, 0.f);
        float dist = __fsqrt_rn(d2g) + __fsqrt_rn(d2r);
        ob[(size_t)o * P] = __expf(ninv * dist * dist);
    }
}

extern "C" void kernel_launch(void* const* d_in, const int* in_sizes, int n_in,
                              void* d_out, int out_size, void* d_ws, size_t ws_size,
                              hipStream_t stream) {
    const float* gin  = (const float*)d_in[0];
    const float* rin  = (const float*)d_in[1];
    const float* gw   = (const float*)d_in[2];
    const float* rw   = (const float*)d_in[3];
    const float* stdp = (const float*)d_in[4];
    float* out = (float*)d_out;

    const int B  = in_sizes[0] / (H * W);   // 32
    const int BP = B * P;                   // 373248

    if (ws_size >= WS_BYTES && d_ws != nullptr && BP % 64 == 0) {
        prep_weights_mfma<<<1, 256, 0, stream>>>(gw, rw, d_ws);
        const int blocks = BP / 64;                 // 5832
        rbf_mfma_t<<<blocks, 256, 0, stream>>>(gin, rin, d_ws, stdp, out);
    } else {
        const int block = 256;
        const int grid  = (BP + block - 1) / block;
        rbf_conv_fallback<<<grid, block, 0, stream>>>(gin, rin, gw, rw, stdp, out, B);
    }
}